// Round 5
// baseline (1016.993 us; speedup 1.0000x reference)
//
#include <hip/hip_runtime.h>
#include <stdint.h>

#define HIDD 128
#define NNODES 100000
#define NEDGES 800000

typedef short s16x8 __attribute__((ext_vector_type(8)));
typedef float f32x4 __attribute__((ext_vector_type(4)));

__device__ __forceinline__ short f2bf(float f) {
  union { float f; unsigned u; } v; v.f = f;
  return (short)((v.u + 0x7fffu + ((v.u >> 16) & 1u)) >> 16);
}
__device__ __forceinline__ short4 cvt4(float4 v) {
  short4 s; s.x = f2bf(v.x); s.y = f2bf(v.y); s.z = f2bf(v.z); s.w = f2bf(v.w);
  return s;
}
__device__ __forceinline__ float bflo(unsigned w) {
  union { unsigned u; float f; } v; v.u = w << 16; return v.f;
}
__device__ __forceinline__ float bfhi(unsigned w) {
  union { unsigned u; float f; } v; v.u = w & 0xffff0000u; return v.f;
}
__device__ __forceinline__ unsigned pack2(float a, float b) {
  return ((unsigned)(unsigned short)f2bf(b) << 16) | (unsigned)(unsigned short)f2bf(a);
}
__device__ __forceinline__ s16x8 cvt8(const float* p) {
  float4 v0 = *(const float4*)p, v1 = *(const float4*)(p + 4);
  union { s16x8 s; uint4 u; } r;
  r.u = make_uint4(pack2(v0.x, v0.y), pack2(v0.z, v0.w),
                   pack2(v1.x, v1.y), pack2(v1.z, v1.w));
  return r.s;
}
__device__ __forceinline__ f32x4 mfma16(s16x8 a, s16x8 b, f32x4 c) {
  return __builtin_amdgcn_mfma_f32_16x16x32_bf16(a, b, c, 0, 0, 0);
}
__device__ __forceinline__ void atomic_pk_bf16(unsigned short* addr, unsigned pk) {
  asm volatile("global_atomic_pk_add_bf16 %0, %1, off" :: "v"(addr), "v"(pk) : "memory");
}

// ---------- prep: h -> bf16 ----------
__global__ void k_prep_h(const float4* __restrict__ h4, short4* __restrict__ hb4, int n4) {
  int stride = gridDim.x * blockDim.x;
  for (int i = blockIdx.x * blockDim.x + threadIdx.x; i < n4; i += stride)
    hb4[i] = cvt4(h4[i]);
}

// ---------- prep: weights -> bf16 [out][in]; w2e additionally col-permuted ----------
__global__ void k_prep_w(const float* __restrict__ w1e, const float* __restrict__ w2e,
                         const float* __restrict__ w1u, const float* __restrict__ w2u,
                         short* __restrict__ w1et, short* __restrict__ w2et,
                         short* __restrict__ w1ut, short* __restrict__ w2ut) {
  int i = blockIdx.x * 256 + threadIdx.x;
  if (i < 49152) {               // dest [128][384]: n=i/384, k=i%384
    int n = i / 384, k = i - n * 384;
    w1et[i] = f2bf(w1e[k * 128 + n]);
    w1ut[i] = f2bf(w1u[k * 128 + n]);
  } else {
    int j = i - 49152;
    if (j < 16384) {             // dest [128][128]: n=j>>7, k=j&127
      int n = j >> 7, k = j & 127;
      int oc = (n & ~31) + 2 * (n & 15) + ((n >> 4) & 1);
      w2et[j] = f2bf(w2e[k * 128 + oc]);   // permuted for pk-atomic epilogue
      w2ut[j] = f2bf(w2u[k * 128 + n]);    // natural
    }
  }
}

// ---------- edge: LDS-staged h gather (once/block), ex direct-stream, 3 blocks/CU ----------
__global__ __launch_bounds__(256, 3)
void k_edge(const short* __restrict__ hb, const int* __restrict__ eidx,
            const float* __restrict__ ex,
            const short* __restrict__ w1t, const short* __restrict__ w2t,
            const float* __restrict__ b1g, const float* __restrict__ b2g,
            unsigned short* __restrict__ incb, unsigned short* __restrict__ outgb,
            float* __restrict__ indeg, float* __restrict__ outdeg) {
  __shared__ __align__(16) short Xs[64][264];   // h[src]|h[dst], 33792 B
  __shared__ __align__(16) short Hs[64][136];   // hidden bf16,  17408 B

  const int tid = threadIdx.x;
  const int wave = tid >> 6, lane = tid & 63;
  const int lg = lane >> 4, lr = lane & 15;
  const int koff = lg * 8;
  const int c0 = wave * 32 + lr, c1 = c0 + 16;   // layer-1 (natural) cols
  const int pc0 = wave * 32 + 2 * lr;            // layer-2 physical col (even)

  // register-resident weights: W1 24 + W2 8 fragments = 128 VGPRs
  s16x8 wb1a[12], wb1b[12], wb2a[4], wb2b[4];
#pragma unroll
  for (int kk = 0; kk < 12; ++kk) {
    wb1a[kk] = *(const s16x8*)(w1t + c0 * 384 + kk * 32 + koff);
    wb1b[kk] = *(const s16x8*)(w1t + c1 * 384 + kk * 32 + koff);
  }
#pragma unroll
  for (int kk = 0; kk < 4; ++kk) {
    wb2a[kk] = *(const s16x8*)(w2t + c0 * 128 + kk * 32 + koff);
    wb2b[kk] = *(const s16x8*)(w2t + c1 * 128 + kk * 32 + koff);
  }
  const float bias1_0 = b1g[c0], bias1_1 = b1g[c1];
  const float bias2_0 = b2g[pc0], bias2_1 = b2g[pc0 + 1];

  for (int t = blockIdx.x; t < NEDGES / 64; t += gridDim.x) {
    const int base = t * 64;

    // Phase A: gather h[src]|h[dst] into Xs — each random row read ONCE,
    // coalesced 256B (R4 lesson: never gather per-wave).
    for (int u = tid; u < 64 * 32; u += 256) {
      int r = u >> 5, c = u & 31;
      int node = (c < 16) ? eidx[base + r] : eidx[NEDGES + base + r];
      *(int4*)&Xs[r][c * 8] = *(const int4*)(hb + (long)node * 128 + (c & 15) * 8);
    }
    if (tid < 64) {
      atomicAdd(&outdeg[eidx[base + tid]], 1.0f);
      atomicAdd(&indeg[eidx[NEDGES + base + tid]], 1.0f);
    }
    __syncthreads();

    // Phase B: layer 1. K 0..255 from LDS, K 256..383 (edge_x) streamed from
    // global per-lane (tile-local 32KB region, 4-wave redundancy L2-absorbed).
    f32x4 acc[4][2] = {};
#pragma unroll
    for (int m = 0; m < 4; ++m) {
      const int row = m * 16 + lr;
      const float* pe = ex + (long)(base + row) * 128 + koff;
#pragma unroll
      for (int kk = 0; kk < 4; ++kk) {
        s16x8 a = *(const s16x8*)&Xs[row][kk * 32 + koff];
        acc[m][0] = mfma16(a, wb1a[kk], acc[m][0]);
        acc[m][1] = mfma16(a, wb1b[kk], acc[m][1]);
      }
#pragma unroll
      for (int kk = 0; kk < 4; ++kk) {
        s16x8 a = *(const s16x8*)&Xs[row][128 + kk * 32 + koff];
        acc[m][0] = mfma16(a, wb1a[4 + kk], acc[m][0]);
        acc[m][1] = mfma16(a, wb1b[4 + kk], acc[m][1]);
      }
#pragma unroll
      for (int kk = 0; kk < 4; ++kk) {
        s16x8 a = cvt8(pe + kk * 32);
        acc[m][0] = mfma16(a, wb1a[8 + kk], acc[m][0]);
        acc[m][1] = mfma16(a, wb1b[8 + kk], acc[m][1]);
      }
    }
#pragma unroll
    for (int m = 0; m < 4; ++m)
#pragma unroll
      for (int r2 = 0; r2 < 4; ++r2) {
        int row = m * 16 + lg * 4 + r2;
        Hs[row][c0] = f2bf(fmaxf(acc[m][0][r2] + bias1_0, 0.f));
        Hs[row][c1] = f2bf(fmaxf(acc[m][1][r2] + bias1_1, 0.f));
      }
    __syncthreads();   // Hs ready; Xs reads retired

    // Phase C: layer 2 (col-permuted W2) + pk-bf16 atomic scatter
    f32x4 acc2[4][2] = {};
#pragma unroll
    for (int kk = 0; kk < 4; ++kk) {
#pragma unroll
      for (int m = 0; m < 4; ++m) {
        s16x8 a = *(const s16x8*)&Hs[m * 16 + lr][kk * 32 + koff];
        acc2[m][0] = mfma16(a, wb2a[kk], acc2[m][0]);
        acc2[m][1] = mfma16(a, wb2b[kk], acc2[m][1]);
      }
    }
#pragma unroll
    for (int m = 0; m < 4; ++m)
#pragma unroll
      for (int r2 = 0; r2 < 4; ++r2) {
        int row = m * 16 + lg * 4 + r2;
        int s = eidx[base + row], d = eidx[NEDGES + base + row];
        unsigned pk = pack2(acc2[m][0][r2] + bias2_0, acc2[m][1][r2] + bias2_1);
        atomic_pk_bf16(outgb + (long)s * 128 + pc0, pk);
        atomic_pk_bf16(incb + (long)d * 128 + pc0, pk);
      }
    // next tile's Xs staging safe: all waves passed the Hs barrier
  }
}

// ---------- node: X=[hb | inc/deg | outg/deg] -> MLP -> residual+LN ----------
__global__ __launch_bounds__(256, 2)
void k_node(const float* __restrict__ h, const short* __restrict__ hb,
            const unsigned short* __restrict__ incb,
            const unsigned short* __restrict__ outgb,
            const float* __restrict__ indeg, const float* __restrict__ outdeg,
            const short* __restrict__ w1t, const short* __restrict__ w2t,
            const float* __restrict__ b1g, const float* __restrict__ b2g,
            const float* __restrict__ lng, const float* __restrict__ lnb,
            float* __restrict__ out) {
  __shared__ __align__(16) char smem[67584];
  short (*Xs)[392] = (short (*)[392])smem;            // 50176 B
  float (*Xf)[132] = (float (*)[132])smem;            // 33792 B, overlays Xs
  short (*Hs)[136] = (short (*)[136])(smem + 50176);  // 17408 B

  const int tid = threadIdx.x;
  const int wave = tid >> 6, lane = tid & 63;
  const int lg = lane >> 4, lr = lane & 15;
  const int koff = lg * 8;
  const int c0 = wave * 32 + lr, c1 = c0 + 16;

  s16x8 wb1a[12], wb1b[12], wb2a[4], wb2b[4];
#pragma unroll
  for (int kk = 0; kk < 12; ++kk) {
    wb1a[kk] = *(const s16x8*)(w1t + c0 * 384 + kk * 32 + koff);
    wb1b[kk] = *(const s16x8*)(w1t + c1 * 384 + kk * 32 + koff);
  }
#pragma unroll
  for (int kk = 0; kk < 4; ++kk) {
    wb2a[kk] = *(const s16x8*)(w2t + c0 * 128 + kk * 32 + koff);
    wb2b[kk] = *(const s16x8*)(w2t + c1 * 128 + kk * 32 + koff);
  }
  const float bias1_0 = b1g[c0], bias1_1 = b1g[c1];
  const float bias2_0 = b2g[c0], bias2_1 = b2g[c1];

  const int ntiles = (NNODES + 63) / 64;
  for (int t = blockIdx.x; t < ntiles; t += gridDim.x) {
    const int base = t * 64;

    for (int u = tid; u < 64 * 16; u += 256) {     // hb straight copy
      int r = u >> 4, c = u & 15;
      long node = min(base + r, NNODES - 1);
      *(int4*)&Xs[r][c * 8] = *(const int4*)(hb + node * 128 + c * 8);
    }
    for (int u = tid; u < 64 * 16; u += 256) {     // incb scaled
      int r = u >> 4, c = u & 15;
      long node = min(base + r, NNODES - 1);
      float s = 1.f / fmaxf(indeg[node], 1.f);
      uint4 w = *(const uint4*)(incb + node * 128 + c * 8);
      unsigned o0 = pack2(bflo(w.x) * s, bfhi(w.x) * s);
      unsigned o1 = pack2(bflo(w.y) * s, bfhi(w.y) * s);
      unsigned o2 = pack2(bflo(w.z) * s, bfhi(w.z) * s);
      unsigned o3 = pack2(bflo(w.w) * s, bfhi(w.w) * s);
      *(uint4*)&Xs[r][128 + c * 8] = make_uint4(o0, o1, o2, o3);
    }
    for (int u = tid; u < 64 * 16; u += 256) {     // outgb scaled
      int r = u >> 4, c = u & 15;
      long node = min(base + r, NNODES - 1);
      float s = 1.f / fmaxf(outdeg[node], 1.f);
      uint4 w = *(const uint4*)(outgb + node * 128 + c * 8);
      unsigned o0 = pack2(bflo(w.x) * s, bfhi(w.x) * s);
      unsigned o1 = pack2(bflo(w.y) * s, bfhi(w.y) * s);
      unsigned o2 = pack2(bflo(w.z) * s, bfhi(w.z) * s);
      unsigned o3 = pack2(bflo(w.w) * s, bfhi(w.w) * s);
      *(uint4*)&Xs[r][256 + c * 8] = make_uint4(o0, o1, o2, o3);
    }
    __syncthreads();

    f32x4 acc[4][2] = {};
#pragma unroll
    for (int kk = 0; kk < 12; ++kk) {
      int k0 = kk * 32 + koff;
#pragma unroll
      for (int m = 0; m < 4; ++m) {
        s16x8 a = *(const s16x8*)&Xs[m * 16 + lr][k0];
        acc[m][0] = mfma16(a, wb1a[kk], acc[m][0]);
        acc[m][1] = mfma16(a, wb1b[kk], acc[m][1]);
      }
    }
#pragma unroll
    for (int m = 0; m < 4; ++m)
#pragma unroll
      for (int r2 = 0; r2 < 4; ++r2) {
        int row = m * 16 + lg * 4 + r2;
        Hs[row][c0] = f2bf(fmaxf(acc[m][0][r2] + bias1_0, 0.f));
        Hs[row][c1] = f2bf(fmaxf(acc[m][1][r2] + bias1_1, 0.f));
      }
    __syncthreads();

    f32x4 acc2[4][2] = {};
#pragma unroll
    for (int kk = 0; kk < 4; ++kk) {
      int k0 = kk * 32 + koff;
#pragma unroll
      for (int m = 0; m < 4; ++m) {
        s16x8 a = *(const s16x8*)&Hs[m * 16 + lr][k0];
        acc2[m][0] = mfma16(a, wb2a[kk], acc2[m][0]);
        acc2[m][1] = mfma16(a, wb2b[kk], acc2[m][1]);
      }
    }
#pragma unroll
    for (int m = 0; m < 4; ++m)
#pragma unroll
      for (int r2 = 0; r2 < 4; ++r2) {
        int row = m * 16 + lg * 4 + r2;
        long node = base + row;
        float h0 = 0.f, h1 = 0.f;
        if (node < NNODES) { h0 = h[node * 128 + c0]; h1 = h[node * 128 + c1]; }
        Xf[row][c0] = acc2[m][0][r2] + bias2_0 + h0;
        Xf[row][c1] = acc2[m][1][r2] + bias2_1 + h1;
      }
    __syncthreads();

    {
      int r = tid >> 2, q = tid & 3;
      float sum = 0.f, ss = 0.f;
      float4 vals[8];
#pragma unroll
      for (int j = 0; j < 8; ++j) {
        float4 v = *(const float4*)&Xf[r][q * 32 + j * 4];
        vals[j] = v;
        sum += v.x + v.y + v.z + v.w;
        ss += v.x * v.x + v.y * v.y + v.z * v.z + v.w * v.w;
      }
      sum += __shfl_xor(sum, 1); sum += __shfl_xor(sum, 2);
      ss  += __shfl_xor(ss, 1);  ss  += __shfl_xor(ss, 2);
      float mean = sum * (1.f / 128.f);
      float var = ss * (1.f / 128.f) - mean * mean;
      float rstd = rsqrtf(var + 1e-5f);
      long node = base + r;
      if (node < NNODES) {
#pragma unroll
        for (int j = 0; j < 8; ++j) {
          int cc = q * 32 + j * 4;
          float4 v = vals[j];
          float4 o;
          o.x = (v.x - mean) * rstd * lng[cc + 0] + lnb[cc + 0];
          o.y = (v.y - mean) * rstd * lng[cc + 1] + lnb[cc + 1];
          o.z = (v.z - mean) * rstd * lng[cc + 2] + lnb[cc + 2];
          o.w = (v.w - mean) * rstd * lng[cc + 3] + lnb[cc + 3];
          *(float4*)(out + node * 128 + cc) = o;
        }
      }
    }
    __syncthreads();
  }
}

extern "C" void kernel_launch(void* const* d_in, const int* in_sizes, int n_in,
                              void* d_out, int out_size, void* d_ws, size_t ws_size,
                              hipStream_t stream) {
  const float* h    = (const float*)d_in[0];
  const int*   ei   = (const int*)d_in[1];
  const float* ex   = (const float*)d_in[2];
  const float* epw1 = (const float*)d_in[3];
  const float* epb1 = (const float*)d_in[4];
  const float* epw2 = (const float*)d_in[5];
  const float* epb2 = (const float*)d_in[6];
  const float* upw1 = (const float*)d_in[7];
  const float* upb1 = (const float*)d_in[8];
  const float* upw2 = (const float*)d_in[9];
  const float* upb2 = (const float*)d_in[10];
  const float* lng  = (const float*)d_in[11];
  const float* lnb  = (const float*)d_in[12];
  float* out = (float*)d_out;

  char* ws = (char*)d_ws;
  unsigned short* incb  = (unsigned short*)(ws);             // 25,600,000 B
  unsigned short* outgb = (unsigned short*)(ws + 25600000);  // 25,600,000 B
  float* indeg  = (float*)(ws + 51200000);                   //    400,000 B
  float* outdeg = (float*)(ws + 51600000);                   //    400,000 B
  short* hb     = (short*)(ws + 52000000);                   // 25,600,000 B
  short* w1et   = (short*)(ws + 77600000);                   //     98,304 B
  short* w2et   = (short*)(ws + 77698304);                   //     32,768 B
  short* w1ut   = (short*)(ws + 77731072);                   //     98,304 B
  short* w2ut   = (short*)(ws + 77829376);                   //     32,768 B

  hipMemsetAsync(ws, 0, 52000000, stream);   // incb+outgb+degrees
  hipLaunchKernelGGL(k_prep_h, dim3(2048), dim3(256), 0, stream,
                     (const float4*)h, (short4*)hb, NNODES * 128 / 4);
  hipLaunchKernelGGL(k_prep_w, dim3(256), dim3(256), 0, stream,
                     epw1, epw2, upw1, upw2, w1et, w2et, w1ut, w2ut);
  hipLaunchKernelGGL(k_edge, dim3(768), dim3(256), 0, stream,
                     hb, ei, ex, w1et, w2et, epb1, epb2, incb, outgb, indeg, outdeg);
  hipLaunchKernelGGL(k_node, dim3(512), dim3(256), 0, stream,
                     h, hb, incb, outgb, indeg, outdeg, w1ut, w2ut, upb1, upb2,
                     lng, lnb, out);
}

// Round 6
// 756.339 us; speedup vs baseline: 1.3446x; 1.3446x over previous
//
#include <hip/hip_runtime.h>
#include <stdint.h>

#define HIDD 128
#define NNODES 100000
#define NEDGES 800000
#define NSEG 196          // ceil(100000/512) segments for the scan

typedef short s16x8 __attribute__((ext_vector_type(8)));
typedef float f32x4 __attribute__((ext_vector_type(4)));

__device__ __forceinline__ short f2bf(float f) {
  union { float f; unsigned u; } v; v.f = f;
  return (short)((v.u + 0x7fffu + ((v.u >> 16) & 1u)) >> 16);
}
__device__ __forceinline__ short4 cvt4(float4 v) {
  short4 s; s.x = f2bf(v.x); s.y = f2bf(v.y); s.z = f2bf(v.z); s.w = f2bf(v.w);
  return s;
}
__device__ __forceinline__ float bflo(unsigned w) {
  union { unsigned u; float f; } v; v.u = w << 16; return v.f;
}
__device__ __forceinline__ float bfhi(unsigned w) {
  union { unsigned u; float f; } v; v.u = w & 0xffff0000u; return v.f;
}
__device__ __forceinline__ unsigned pack2(float a, float b) {
  return ((unsigned)(unsigned short)f2bf(b) << 16) | (unsigned)(unsigned short)f2bf(a);
}
__device__ __forceinline__ f32x4 mfma16(s16x8 a, s16x8 b, f32x4 c) {
  return __builtin_amdgcn_mfma_f32_16x16x32_bf16(a, b, c, 0, 0, 0);
}
__device__ __forceinline__ void atomic_pk_bf16(unsigned short* addr, unsigned pk) {
  asm volatile("global_atomic_pk_add_bf16 %0, %1, off" :: "v"(addr), "v"(pk) : "memory");
}

// ---------- prep: h -> bf16 ----------
__global__ void k_prep_h(const float4* __restrict__ h4, short4* __restrict__ hb4, int n4) {
  int stride = gridDim.x * blockDim.x;
  for (int i = blockIdx.x * blockDim.x + threadIdx.x; i < n4; i += stride)
    hb4[i] = cvt4(h4[i]);
}

// ---------- prep: weights -> bf16 [out][in]; w2e col-permuted so that ----------
// lane fragments (frag0,frag1) = natural cols (band+2lr, band+2lr+1).
__global__ void k_prep_w(const float* __restrict__ w1e, const float* __restrict__ w2e,
                         const float* __restrict__ w1u, const float* __restrict__ w2u,
                         short* __restrict__ w1et, short* __restrict__ w2et,
                         short* __restrict__ w1ut, short* __restrict__ w2ut) {
  int i = blockIdx.x * 256 + threadIdx.x;
  if (i < 49152) {               // dest [128][384]: n=i/384, k=i%384
    int n = i / 384, k = i - n * 384;
    w1et[i] = f2bf(w1e[k * 128 + n]);
    w1ut[i] = f2bf(w1u[k * 128 + n]);
  } else {
    int j = i - 49152;
    if (j < 16384) {             // dest [128][128]: n=j>>7, k=j&127
      int n = j >> 7, k = j & 127;
      int oc = (n & ~31) + 2 * (n & 15) + ((n >> 4) & 1);
      w2et[j] = f2bf(w2e[k * 128 + oc]);   // permuted
      w2ut[j] = f2bf(w2u[k * 128 + n]);    // natural
    }
  }
}

// ================= counting-sort chain (both directions) =================
__global__ void k_hist(const int* __restrict__ eidx, int* __restrict__ cnt_s,
                       int* __restrict__ cnt_d) {
  int i = blockIdx.x * 256 + threadIdx.x;
  if (i < NEDGES) {
    atomicAdd(&cnt_s[eidx[i]], 1);
    atomicAdd(&cnt_d[eidx[NEDGES + i]], 1);
  }
}

// per-segment totals (512 elems/segment); blocks [0,NSEG)=cnt_d, [NSEG,2N)=cnt_s
__global__ void k_bsum(const int* __restrict__ cnt_d, const int* __restrict__ cnt_s,
                       int* __restrict__ bsum) {
  __shared__ int red[256];
  int gb = blockIdx.x, sel = gb >= NSEG, b = gb - sel * NSEG;
  const int* cnt = sel ? cnt_s : cnt_d;
  int t = threadIdx.x;
  int i0 = b * 512 + 2 * t;
  int a = (i0 < NNODES) ? cnt[i0] : 0;
  int c = (i0 + 1 < NNODES) ? cnt[i0 + 1] : 0;
  red[t] = a + c;
  __syncthreads();
  for (int d = 128; d > 0; d >>= 1) {
    if (t < d) red[t] += red[t + d];
    __syncthreads();
  }
  if (t == 0) bsum[gb] = red[0];
}

// serial exclusive scan of segment totals (2*NSEG=392 values) + sentinels
__global__ void k_soff(int* __restrict__ bsum, int* __restrict__ off_d,
                       int* __restrict__ off_s) {
  if (threadIdx.x == 0) {
    int tot = 0;
    for (int i = 0; i < NSEG; ++i) { int v = bsum[i]; bsum[i] = tot; tot += v; }
    off_d[NNODES] = tot;
  } else if (threadIdx.x == 1) {
    int tot = 0;
    for (int i = NSEG; i < 2 * NSEG; ++i) { int v = bsum[i]; bsum[i] = tot; tot += v; }
    off_s[NNODES] = tot;
  }
}

// per-segment exclusive scan + segment offset -> off, cur
__global__ void k_sfin(const int* __restrict__ cnt_d, const int* __restrict__ cnt_s,
                       const int* __restrict__ bsum,
                       int* __restrict__ off_d, int* __restrict__ off_s,
                       int* __restrict__ cur_d, int* __restrict__ cur_s) {
  __shared__ int p[256];
  int gb = blockIdx.x, sel = gb >= NSEG, b = gb - sel * NSEG;
  const int* cnt = sel ? cnt_s : cnt_d;
  int* off = sel ? off_s : off_d;
  int* cur = sel ? cur_s : cur_d;
  int t = threadIdx.x;
  int i0 = b * 512 + 2 * t;
  int a = (i0 < NNODES) ? cnt[i0] : 0;
  int c = (i0 + 1 < NNODES) ? cnt[i0 + 1] : 0;
  p[t] = a + c;
  __syncthreads();
  for (int d = 1; d < 256; d <<= 1) {
    int v = (t >= d) ? p[t - d] : 0;
    __syncthreads();
    p[t] += v;
    __syncthreads();
  }
  int excl = (t ? p[t - 1] : 0) + bsum[gb];
  if (i0 < NNODES)     { off[i0] = excl;     cur[i0] = excl; }
  if (i0 + 1 < NNODES) { off[i0 + 1] = excl + a; cur[i0 + 1] = excl + a; }
}

__global__ void k_scat(const int* __restrict__ eidx, int* __restrict__ cur_s,
                       int* __restrict__ cur_d, int* __restrict__ slist,
                       int* __restrict__ dlist) {
  int i = blockIdx.x * 256 + threadIdx.x;
  if (i < NEDGES) {
    slist[atomicAdd(&cur_s[eidx[i]], 1)] = i;
    dlist[atomicAdd(&cur_d[eidx[NEDGES + i]], 1)] = i;
  }
}

// ================= new path: edge MLP -> message store (no atomics) =================
__global__ __launch_bounds__(256, 2)
void k_edge2(const short* __restrict__ hb, const int* __restrict__ eidx,
             const float* __restrict__ ex,
             const short* __restrict__ w1t, const short* __restrict__ w2t,
             const float* __restrict__ b1g, const float* __restrict__ b2g,
             unsigned* __restrict__ msgd) {
  __shared__ __align__(16) short Xs[64][392];   // 50176 B
  __shared__ __align__(16) short Hs[64][136];   // 17408 B

  const int tid = threadIdx.x;
  const int wave = tid >> 6, lane = tid & 63;
  const int lg = lane >> 4, lr = lane & 15;
  const int koff = lg * 8;
  const int c0 = wave * 32 + lr, c1 = c0 + 16;
  const int pc0 = wave * 32 + 2 * lr;   // natural col of frag0 (permuted W2)

  s16x8 wb1a[12], wb1b[12], wb2a[4], wb2b[4];
#pragma unroll
  for (int kk = 0; kk < 12; ++kk) {
    wb1a[kk] = *(const s16x8*)(w1t + c0 * 384 + kk * 32 + koff);
    wb1b[kk] = *(const s16x8*)(w1t + c1 * 384 + kk * 32 + koff);
  }
#pragma unroll
  for (int kk = 0; kk < 4; ++kk) {
    wb2a[kk] = *(const s16x8*)(w2t + c0 * 128 + kk * 32 + koff);
    wb2b[kk] = *(const s16x8*)(w2t + c1 * 128 + kk * 32 + koff);
  }
  const float bias1_0 = b1g[c0], bias1_1 = b1g[c1];
  const float bias2_0 = b2g[pc0], bias2_1 = b2g[pc0 + 1];

  for (int t = blockIdx.x; t < NEDGES / 64; t += gridDim.x) {
    const int base = t * 64;

    // Phase A: stage EVERYTHING through LDS once per block (R4/R5 lesson)
    for (int u = tid; u < 64 * 32; u += 256) {
      int r = u >> 5, c = u & 31;
      int node = (c < 16) ? eidx[base + r] : eidx[NEDGES + base + r];
      *(int4*)&Xs[r][c * 8] = *(const int4*)(hb + (long)node * 128 + (c & 15) * 8);
    }
    for (int u = tid; u < 64 * 32; u += 256) {
      int r = u >> 5, q = u & 31;
      float4 v = *(const float4*)(ex + (long)(base + r) * 128 + q * 4);
      *(short4*)&Xs[r][256 + q * 4] = cvt4(v);
    }
    __syncthreads();

    // Phase B: layer 1 + relu -> Hs
    f32x4 acc[4][2] = {};
#pragma unroll
    for (int kk = 0; kk < 12; ++kk) {
      int k0 = kk * 32 + koff;
#pragma unroll
      for (int m = 0; m < 4; ++m) {
        s16x8 a = *(const s16x8*)&Xs[m * 16 + lr][k0];
        acc[m][0] = mfma16(a, wb1a[kk], acc[m][0]);
        acc[m][1] = mfma16(a, wb1b[kk], acc[m][1]);
      }
    }
#pragma unroll
    for (int m = 0; m < 4; ++m)
#pragma unroll
      for (int r2 = 0; r2 < 4; ++r2) {
        int row = m * 16 + lg * 4 + r2;
        Hs[row][c0] = f2bf(fmaxf(acc[m][0][r2] + bias1_0, 0.f));
        Hs[row][c1] = f2bf(fmaxf(acc[m][1][r2] + bias1_1, 0.f));
      }
    __syncthreads();

    // Phase C: layer 2 + coalesced message store (natural col order)
    f32x4 acc2[4][2] = {};
#pragma unroll
    for (int kk = 0; kk < 4; ++kk) {
#pragma unroll
      for (int m = 0; m < 4; ++m) {
        s16x8 a = *(const s16x8*)&Hs[m * 16 + lr][kk * 32 + koff];
        acc2[m][0] = mfma16(a, wb2a[kk], acc2[m][0]);
        acc2[m][1] = mfma16(a, wb2b[kk], acc2[m][1]);
      }
    }
#pragma unroll
    for (int m = 0; m < 4; ++m)
#pragma unroll
      for (int r2 = 0; r2 < 4; ++r2) {
        int row = m * 16 + lg * 4 + r2;
        msgd[(long)(base + row) * 64 + wave * 16 + lr] =
            pack2(acc2[m][0][r2] + bias2_0, acc2[m][1][r2] + bias2_1);
      }
  }
}

// ================= new path: CSR gather-aggregate + node MLP + LN =================
__global__ __launch_bounds__(256, 2)
void k_node2(const float* __restrict__ h, const short* __restrict__ hb,
             const unsigned short* __restrict__ msg,
             const int* __restrict__ off_d, const int* __restrict__ dlist,
             const int* __restrict__ off_s, const int* __restrict__ slist,
             const short* __restrict__ w1t, const short* __restrict__ w2t,
             const float* __restrict__ b1g, const float* __restrict__ b2g,
             const float* __restrict__ lng, const float* __restrict__ lnb,
             float* __restrict__ out) {
  __shared__ __align__(16) char smem[67584];
  short (*Xs)[392] = (short (*)[392])smem;            // 50176 B
  float (*Xf)[132] = (float (*)[132])smem;            // overlay
  short (*Hs)[136] = (short (*)[136])(smem + 50176);  // 17408 B

  const int tid = threadIdx.x;
  const int wave = tid >> 6, lane = tid & 63;
  const int lg = lane >> 4, lr = lane & 15;
  const int koff = lg * 8;
  const int c0 = wave * 32 + lr, c1 = c0 + 16;

  s16x8 wb1a[12], wb1b[12], wb2a[4], wb2b[4];
#pragma unroll
  for (int kk = 0; kk < 12; ++kk) {
    wb1a[kk] = *(const s16x8*)(w1t + c0 * 384 + kk * 32 + koff);
    wb1b[kk] = *(const s16x8*)(w1t + c1 * 384 + kk * 32 + koff);
  }
#pragma unroll
  for (int kk = 0; kk < 4; ++kk) {
    wb2a[kk] = *(const s16x8*)(w2t + c0 * 128 + kk * 32 + koff);
    wb2b[kk] = *(const s16x8*)(w2t + c1 * 128 + kk * 32 + koff);
  }
  const float bias1_0 = b1g[c0], bias1_1 = b1g[c1];
  const float bias2_0 = b2g[c0], bias2_1 = b2g[c1];

  const int ntiles = (NNODES + 63) / 64;
  for (int t = blockIdx.x; t < ntiles; t += gridDim.x) {
    const int base = t * 64;

    // h copy
    for (int u = tid; u < 64 * 16; u += 256) {
      int r = u >> 4, c = u & 15;
      long node = min(base + r, NNODES - 1);
      *(int4*)&Xs[r][c * 8] = *(const int4*)(hb + node * 128 + c * 8);
    }
    // CSR aggregation: 4 threads per node, 32 cols each, f32 accumulate
    {
      int r = tid >> 2, q = tid & 3;
      long node = base + r;
      bool valid = node < NNODES;
#pragma unroll
      for (int dir = 0; dir < 2; ++dir) {
        const int* off = dir ? off_s : off_d;
        const int* lst = dir ? slist : dlist;
        float av[32];
#pragma unroll
        for (int j = 0; j < 32; ++j) av[j] = 0.f;
        int e0 = 0, e1 = 0;
        if (valid) { e0 = off[node]; e1 = off[node + 1]; }
        for (int e = e0; e < e1; ++e) {
          int eid = lst[e];
          const uint4* mp = (const uint4*)(msg + (long)eid * 128 + q * 32);
          uint4 u0 = mp[0], u1 = mp[1], u2 = mp[2], u3 = mp[3];
          av[0]  += bflo(u0.x); av[1]  += bfhi(u0.x);
          av[2]  += bflo(u0.y); av[3]  += bfhi(u0.y);
          av[4]  += bflo(u0.z); av[5]  += bfhi(u0.z);
          av[6]  += bflo(u0.w); av[7]  += bfhi(u0.w);
          av[8]  += bflo(u1.x); av[9]  += bfhi(u1.x);
          av[10] += bflo(u1.y); av[11] += bfhi(u1.y);
          av[12] += bflo(u1.z); av[13] += bfhi(u1.z);
          av[14] += bflo(u1.w); av[15] += bfhi(u1.w);
          av[16] += bflo(u2.x); av[17] += bfhi(u2.x);
          av[18] += bflo(u2.y); av[19] += bfhi(u2.y);
          av[20] += bflo(u2.z); av[21] += bfhi(u2.z);
          av[22] += bflo(u2.w); av[23] += bfhi(u2.w);
          av[24] += bflo(u3.x); av[25] += bfhi(u3.x);
          av[26] += bflo(u3.y); av[27] += bfhi(u3.y);
          av[28] += bflo(u3.z); av[29] += bfhi(u3.z);
          av[30] += bflo(u3.w); av[31] += bfhi(u3.w);
        }
        float sc = 1.f / fmaxf((float)(e1 - e0), 1.f);
        unsigned pk[16];
#pragma unroll
        for (int j = 0; j < 16; ++j) pk[j] = pack2(av[2 * j] * sc, av[2 * j + 1] * sc);
        uint4* dst = (uint4*)&Xs[r][(dir ? 256 : 128) + q * 32];
        dst[0] = make_uint4(pk[0], pk[1], pk[2], pk[3]);
        dst[1] = make_uint4(pk[4], pk[5], pk[6], pk[7]);
        dst[2] = make_uint4(pk[8], pk[9], pk[10], pk[11]);
        dst[3] = make_uint4(pk[12], pk[13], pk[14], pk[15]);
      }
    }
    __syncthreads();

    // MLP layer 1
    f32x4 acc[4][2] = {};
#pragma unroll
    for (int kk = 0; kk < 12; ++kk) {
      int k0 = kk * 32 + koff;
#pragma unroll
      for (int m = 0; m < 4; ++m) {
        s16x8 a = *(const s16x8*)&Xs[m * 16 + lr][k0];
        acc[m][0] = mfma16(a, wb1a[kk], acc[m][0]);
        acc[m][1] = mfma16(a, wb1b[kk], acc[m][1]);
      }
    }
#pragma unroll
    for (int m = 0; m < 4; ++m)
#pragma unroll
      for (int r2 = 0; r2 < 4; ++r2) {
        int row = m * 16 + lg * 4 + r2;
        Hs[row][c0] = f2bf(fmaxf(acc[m][0][r2] + bias1_0, 0.f));
        Hs[row][c1] = f2bf(fmaxf(acc[m][1][r2] + bias1_1, 0.f));
      }
    __syncthreads();

    // MLP layer 2 + residual -> Xf
    f32x4 acc2[4][2] = {};
#pragma unroll
    for (int kk = 0; kk < 4; ++kk) {
      int k0 = kk * 32 + koff;
#pragma unroll
      for (int m = 0; m < 4; ++m) {
        s16x8 a = *(const s16x8*)&Hs[m * 16 + lr][k0];
        acc2[m][0] = mfma16(a, wb2a[kk], acc2[m][0]);
        acc2[m][1] = mfma16(a, wb2b[kk], acc2[m][1]);
      }
    }
#pragma unroll
    for (int m = 0; m < 4; ++m)
#pragma unroll
      for (int r2 = 0; r2 < 4; ++r2) {
        int row = m * 16 + lg * 4 + r2;
        long node = base + row;
        float h0 = 0.f, h1 = 0.f;
        if (node < NNODES) { h0 = h[node * 128 + c0]; h1 = h[node * 128 + c1]; }
        Xf[row][c0] = acc2[m][0][r2] + bias2_0 + h0;
        Xf[row][c1] = acc2[m][1][r2] + bias2_1 + h1;
      }
    __syncthreads();

    // LayerNorm + store
    {
      int r = tid >> 2, q = tid & 3;
      float sum = 0.f, ss = 0.f;
      float4 vals[8];
#pragma unroll
      for (int j = 0; j < 8; ++j) {
        float4 v = *(const float4*)&Xf[r][q * 32 + j * 4];
        vals[j] = v;
        sum += v.x + v.y + v.z + v.w;
        ss += v.x * v.x + v.y * v.y + v.z * v.z + v.w * v.w;
      }
      sum += __shfl_xor(sum, 1); sum += __shfl_xor(sum, 2);
      ss  += __shfl_xor(ss, 1);  ss  += __shfl_xor(ss, 2);
      float mean = sum * (1.f / 128.f);
      float var = ss * (1.f / 128.f) - mean * mean;
      float rstd = rsqrtf(var + 1e-5f);
      long node = base + r;
      if (node < NNODES) {
#pragma unroll
        for (int j = 0; j < 8; ++j) {
          int cc = q * 32 + j * 4;
          float4 v = vals[j];
          float4 o;
          o.x = (v.x - mean) * rstd * lng[cc + 0] + lnb[cc + 0];
          o.y = (v.y - mean) * rstd * lng[cc + 1] + lnb[cc + 1];
          o.z = (v.z - mean) * rstd * lng[cc + 2] + lnb[cc + 2];
          o.w = (v.w - mean) * rstd * lng[cc + 3] + lnb[cc + 3];
          *(float4*)(out + node * 128 + cc) = o;
        }
      }
    }
    __syncthreads();
  }
}

// ================= fallback path (R3, proven 682 us): atomics =================
__global__ __launch_bounds__(256, 2)
void k_edge_at(const short* __restrict__ hb, const int* __restrict__ eidx,
               const float* __restrict__ ex,
               const short* __restrict__ w1t, const short* __restrict__ w2t,
               const float* __restrict__ b1g, const float* __restrict__ b2g,
               unsigned short* __restrict__ incb, unsigned short* __restrict__ outgb,
               float* __restrict__ indeg, float* __restrict__ outdeg) {
  __shared__ __align__(16) short Xs[64][392];
  __shared__ __align__(16) short Hs[64][136];
  const int tid = threadIdx.x;
  const int wave = tid >> 6, lane = tid & 63;
  const int lg = lane >> 4, lr = lane & 15;
  const int koff = lg * 8;
  const int c0 = wave * 32 + lr, c1 = c0 + 16;
  const int pc0 = wave * 32 + 2 * lr;
  s16x8 wb1a[12], wb1b[12], wb2a[4], wb2b[4];
#pragma unroll
  for (int kk = 0; kk < 12; ++kk) {
    wb1a[kk] = *(const s16x8*)(w1t + c0 * 384 + kk * 32 + koff);
    wb1b[kk] = *(const s16x8*)(w1t + c1 * 384 + kk * 32 + koff);
  }
#pragma unroll
  for (int kk = 0; kk < 4; ++kk) {
    wb2a[kk] = *(const s16x8*)(w2t + c0 * 128 + kk * 32 + koff);
    wb2b[kk] = *(const s16x8*)(w2t + c1 * 128 + kk * 32 + koff);
  }
  const float bias1_0 = b1g[c0], bias1_1 = b1g[c1];
  const float bias2_0 = b2g[pc0], bias2_1 = b2g[pc0 + 1];
  for (int t = blockIdx.x; t < NEDGES / 64; t += gridDim.x) {
    const int base = t * 64;
    for (int u = tid; u < 64 * 32; u += 256) {
      int r = u >> 5, c = u & 31;
      int node = (c < 16) ? eidx[base + r] : eidx[NEDGES + base + r];
      *(int4*)&Xs[r][c * 8] = *(const int4*)(hb + (long)node * 128 + (c & 15) * 8);
    }
    for (int u = tid; u < 64 * 32; u += 256) {
      int r = u >> 5, q = u & 31;
      float4 v = *(const float4*)(ex + (long)(base + r) * 128 + q * 4);
      *(short4*)&Xs[r][256 + q * 4] = cvt4(v);
    }
    if (tid < 64) {
      atomicAdd(&outdeg[eidx[base + tid]], 1.0f);
      atomicAdd(&indeg[eidx[NEDGES + base + tid]], 1.0f);
    }
    __syncthreads();
    f32x4 acc[4][2] = {};
#pragma unroll
    for (int kk = 0; kk < 12; ++kk) {
      int k0 = kk * 32 + koff;
#pragma unroll
      for (int m = 0; m < 4; ++m) {
        s16x8 a = *(const s16x8*)&Xs[m * 16 + lr][k0];
        acc[m][0] = mfma16(a, wb1a[kk], acc[m][0]);
        acc[m][1] = mfma16(a, wb1b[kk], acc[m][1]);
      }
    }
#pragma unroll
    for (int m = 0; m < 4; ++m)
#pragma unroll
      for (int r2 = 0; r2 < 4; ++r2) {
        int row = m * 16 + lg * 4 + r2;
        Hs[row][c0] = f2bf(fmaxf(acc[m][0][r2] + bias1_0, 0.f));
        Hs[row][c1] = f2bf(fmaxf(acc[m][1][r2] + bias1_1, 0.f));
      }
    __syncthreads();
    f32x4 acc2[4][2] = {};
#pragma unroll
    for (int kk = 0; kk < 4; ++kk) {
#pragma unroll
      for (int m = 0; m < 4; ++m) {
        s16x8 a = *(const s16x8*)&Hs[m * 16 + lr][kk * 32 + koff];
        acc2[m][0] = mfma16(a, wb2a[kk], acc2[m][0]);
        acc2[m][1] = mfma16(a, wb2b[kk], acc2[m][1]);
      }
    }
#pragma unroll
    for (int m = 0; m < 4; ++m)
#pragma unroll
      for (int r2 = 0; r2 < 4; ++r2) {
        int row = m * 16 + lg * 4 + r2;
        int s = eidx[base + row], d = eidx[NEDGES + base + row];
        unsigned pk = pack2(acc2[m][0][r2] + bias2_0, acc2[m][1][r2] + bias2_1);
        atomic_pk_bf16(outgb + (long)s * 128 + pc0, pk);
        atomic_pk_bf16(incb + (long)d * 128 + pc0, pk);
      }
  }
}

__global__ __launch_bounds__(256, 2)
void k_node_at(const float* __restrict__ h, const short* __restrict__ hb,
               const unsigned short* __restrict__ incb,
               const unsigned short* __restrict__ outgb,
               const float* __restrict__ indeg, const float* __restrict__ outdeg,
               const short* __restrict__ w1t, const short* __restrict__ w2t,
               const float* __restrict__ b1g, const float* __restrict__ b2g,
               const float* __restrict__ lng, const float* __restrict__ lnb,
               float* __restrict__ out) {
  __shared__ __align__(16) char smem[67584];
  short (*Xs)[392] = (short (*)[392])smem;
  float (*Xf)[132] = (float (*)[132])smem;
  short (*Hs)[136] = (short (*)[136])(smem + 50176);
  const int tid = threadIdx.x;
  const int wave = tid >> 6, lane = tid & 63;
  const int lg = lane >> 4, lr = lane & 15;
  const int koff = lg * 8;
  const int c0 = wave * 32 + lr, c1 = c0 + 16;
  s16x8 wb1a[12], wb1b[12], wb2a[4], wb2b[4];
#pragma unroll
  for (int kk = 0; kk < 12; ++kk) {
    wb1a[kk] = *(const s16x8*)(w1t + c0 * 384 + kk * 32 + koff);
    wb1b[kk] = *(const s16x8*)(w1t + c1 * 384 + kk * 32 + koff);
  }
#pragma unroll
  for (int kk = 0; kk < 4; ++kk) {
    wb2a[kk] = *(const s16x8*)(w2t + c0 * 128 + kk * 32 + koff);
    wb2b[kk] = *(const s16x8*)(w2t + c1 * 128 + kk * 32 + koff);
  }
  const float bias1_0 = b1g[c0], bias1_1 = b1g[c1];
  const float bias2_0 = b2g[c0], bias2_1 = b2g[c1];
  const int ntiles = (NNODES + 63) / 64;
  for (int t = blockIdx.x; t < ntiles; t += gridDim.x) {
    const int base = t * 64;
    for (int u = tid; u < 64 * 16; u += 256) {
      int r = u >> 4, c = u & 15;
      long node = min(base + r, NNODES - 1);
      *(int4*)&Xs[r][c * 8] = *(const int4*)(hb + node * 128 + c * 8);
    }
    for (int u = tid; u < 64 * 16; u += 256) {
      int r = u >> 4, c = u & 15;
      long node = min(base + r, NNODES - 1);
      float s = 1.f / fmaxf(indeg[node], 1.f);
      uint4 w = *(const uint4*)(incb + node * 128 + c * 8);
      *(uint4*)&Xs[r][128 + c * 8] = make_uint4(
        pack2(bflo(w.x) * s, bfhi(w.x) * s), pack2(bflo(w.y) * s, bfhi(w.y) * s),
        pack2(bflo(w.z) * s, bfhi(w.z) * s), pack2(bflo(w.w) * s, bfhi(w.w) * s));
    }
    for (int u = tid; u < 64 * 16; u += 256) {
      int r = u >> 4, c = u & 15;
      long node = min(base + r, NNODES - 1);
      float s = 1.f / fmaxf(outdeg[node], 1.f);
      uint4 w = *(const uint4*)(outgb + node * 128 + c * 8);
      *(uint4*)&Xs[r][256 + c * 8] = make_uint4(
        pack2(bflo(w.x) * s, bfhi(w.x) * s), pack2(bflo(w.y) * s, bfhi(w.y) * s),
        pack2(bflo(w.z) * s, bfhi(w.z) * s), pack2(bflo(w.w) * s, bfhi(w.w) * s));
    }
    __syncthreads();
    f32x4 acc[4][2] = {};
#pragma unroll
    for (int kk = 0; kk < 12; ++kk) {
      int k0 = kk * 32 + koff;
#pragma unroll
      for (int m = 0; m < 4; ++m) {
        s16x8 a = *(const s16x8*)&Xs[m * 16 + lr][k0];
        acc[m][0] = mfma16(a, wb1a[kk], acc[m][0]);
        acc[m][1] = mfma16(a, wb1b[kk], acc[m][1]);
      }
    }
#pragma unroll
    for (int m = 0; m < 4; ++m)
#pragma unroll
      for (int r2 = 0; r2 < 4; ++r2) {
        int row = m * 16 + lg * 4 + r2;
        Hs[row][c0] = f2bf(fmaxf(acc[m][0][r2] + bias1_0, 0.f));
        Hs[row][c1] = f2bf(fmaxf(acc[m][1][r2] + bias1_1, 0.f));
      }
    __syncthreads();
    f32x4 acc2[4][2] = {};
#pragma unroll
    for (int kk = 0; kk < 4; ++kk) {
      int k0 = kk * 32 + koff;
#pragma unroll
      for (int m = 0; m < 4; ++m) {
        s16x8 a = *(const s16x8*)&Hs[m * 16 + lr][k0];
        acc2[m][0] = mfma16(a, wb2a[kk], acc2[m][0]);
        acc2[m][1] = mfma16(a, wb2b[kk], acc2[m][1]);
      }
    }
#pragma unroll
    for (int m = 0; m < 4; ++m)
#pragma unroll
      for (int r2 = 0; r2 < 4; ++r2) {
        int row = m * 16 + lg * 4 + r2;
        long node = base + row;
        float h0 = 0.f, h1 = 0.f;
        if (node < NNODES) { h0 = h[node * 128 + c0]; h1 = h[node * 128 + c1]; }
        Xf[row][c0] = acc2[m][0][r2] + bias2_0 + h0;
        Xf[row][c1] = acc2[m][1][r2] + bias2_1 + h1;
      }
    __syncthreads();
    {
      int r = tid >> 2, q = tid & 3;
      float sum = 0.f, ss = 0.f;
      float4 vals[8];
#pragma unroll
      for (int j = 0; j < 8; ++j) {
        float4 v = *(const float4*)&Xf[r][q * 32 + j * 4];
        vals[j] = v;
        sum += v.x + v.y + v.z + v.w;
        ss += v.x * v.x + v.y * v.y + v.z * v.z + v.w * v.w;
      }
      sum += __shfl_xor(sum, 1); sum += __shfl_xor(sum, 2);
      ss  += __shfl_xor(ss, 1);  ss  += __shfl_xor(ss, 2);
      float mean = sum * (1.f / 128.f);
      float var = ss * (1.f / 128.f) - mean * mean;
      float rstd = rsqrtf(var + 1e-5f);
      long node = base + r;
      if (node < NNODES) {
#pragma unroll
        for (int j = 0; j < 8; ++j) {
          int cc = q * 32 + j * 4;
          float4 v = vals[j];
          float4 o;
          o.x = (v.x - mean) * rstd * lng[cc + 0] + lnb[cc + 0];
          o.y = (v.y - mean) * rstd * lng[cc + 1] + lnb[cc + 1];
          o.z = (v.z - mean) * rstd * lng[cc + 2] + lnb[cc + 2];
          o.w = (v.w - mean) * rstd * lng[cc + 3] + lnb[cc + 3];
          *(float4*)(out + node * 128 + cc) = o;
        }
      }
    }
    __syncthreads();
  }
}

extern "C" void kernel_launch(void* const* d_in, const int* in_sizes, int n_in,
                              void* d_out, int out_size, void* d_ws, size_t ws_size,
                              hipStream_t stream) {
  const float* h    = (const float*)d_in[0];
  const int*   ei   = (const int*)d_in[1];
  const float* ex   = (const float*)d_in[2];
  const float* epw1 = (const float*)d_in[3];
  const float* epb1 = (const float*)d_in[4];
  const float* epw2 = (const float*)d_in[5];
  const float* epb2 = (const float*)d_in[6];
  const float* upw1 = (const float*)d_in[7];
  const float* upb1 = (const float*)d_in[8];
  const float* upw2 = (const float*)d_in[9];
  const float* upb2 = (const float*)d_in[10];
  const float* lng  = (const float*)d_in[11];
  const float* lnb  = (const float*)d_in[12];
  float* out = (float*)d_out;
  char* ws = (char*)d_ws;

  const size_t NEED = 239500000;
  if (ws_size >= NEED) {
    // ---------- CSR path (no value atomics) ----------
    unsigned short* msg = (unsigned short*)(ws);            // 204,800,000
    short* hb    = (short*)(ws + 204800000);                //  25,600,000
    short* w1et  = (short*)(ws + 230400000);                //      98,304
    short* w2et  = (short*)(ws + 230498304);                //      32,768
    short* w1ut  = (short*)(ws + 230531072);                //      98,304
    short* w2ut  = (short*)(ws + 230629376);                //      32,768
    int* cnt_d   = (int*)(ws + 230662144);                  //     400,000
    int* cnt_s   = (int*)(ws + 231062144);                  //     400,000
    int* off_d   = (int*)(ws + 231462144);                  //     400,004
    int* off_s   = (int*)(ws + 231862148);                  //     400,004
    int* cur_d   = (int*)(ws + 232262152);                  //     400,000
    int* cur_s   = (int*)(ws + 232662152);                  //     400,000
    int* dlist   = (int*)(ws + 233062152);                  //   3,200,000
    int* slist   = (int*)(ws + 236262152);                  //   3,200,000
    int* bsum    = (int*)(ws + 239462152);                  //       1,600

    hipMemsetAsync(cnt_d, 0, 800000, stream);               // cnt_d + cnt_s
    hipLaunchKernelGGL(k_prep_h, dim3(2048), dim3(256), 0, stream,
                       (const float4*)h, (short4*)hb, NNODES * 128 / 4);
    hipLaunchKernelGGL(k_prep_w, dim3(256), dim3(256), 0, stream,
                       epw1, epw2, upw1, upw2, w1et, w2et, w1ut, w2ut);
    hipLaunchKernelGGL(k_hist, dim3((NEDGES + 255) / 256), dim3(256), 0, stream,
                       ei, cnt_s, cnt_d);
    hipLaunchKernelGGL(k_bsum, dim3(2 * NSEG), dim3(256), 0, stream,
                       cnt_d, cnt_s, bsum);
    hipLaunchKernelGGL(k_soff, dim3(1), dim3(64), 0, stream, bsum, off_d, off_s);
    hipLaunchKernelGGL(k_sfin, dim3(2 * NSEG), dim3(256), 0, stream,
                       cnt_d, cnt_s, bsum, off_d, off_s, cur_d, cur_s);
    hipLaunchKernelGGL(k_scat, dim3((NEDGES + 255) / 256), dim3(256), 0, stream,
                       ei, cur_s, cur_d, slist, dlist);
    hipLaunchKernelGGL(k_edge2, dim3(1024), dim3(256), 0, stream,
                       hb, ei, ex, w1et, w2et, epb1, epb2, (unsigned*)msg);
    hipLaunchKernelGGL(k_node2, dim3(512), dim3(256), 0, stream,
                       h, hb, msg, off_d, dlist, off_s, slist,
                       w1ut, w2ut, upb1, upb2, lng, lnb, out);
  } else {
    // ---------- fallback: proven R3 atomic path ----------
    unsigned short* incb  = (unsigned short*)(ws);             // 25,600,000
    unsigned short* outgb = (unsigned short*)(ws + 25600000);  // 25,600,000
    float* indeg  = (float*)(ws + 51200000);
    float* outdeg = (float*)(ws + 51600000);
    short* hb     = (short*)(ws + 52000000);
    short* w1et   = (short*)(ws + 77600000);
    short* w2et   = (short*)(ws + 77698304);
    short* w1ut   = (short*)(ws + 77731072);
    short* w2ut   = (short*)(ws + 77829376);

    hipMemsetAsync(ws, 0, 52000000, stream);
    hipLaunchKernelGGL(k_prep_h, dim3(2048), dim3(256), 0, stream,
                       (const float4*)h, (short4*)hb, NNODES * 128 / 4);
    hipLaunchKernelGGL(k_prep_w, dim3(256), dim3(256), 0, stream,
                       epw1, epw2, upw1, upw2, w1et, w2et, w1ut, w2ut);
    hipLaunchKernelGGL(k_edge_at, dim3(1024), dim3(256), 0, stream,
                       hb, ei, ex, w1et, w2et, epb1, epb2, incb, outgb, indeg, outdeg);
    hipLaunchKernelGGL(k_node_at, dim3(512), dim3(256), 0, stream,
                       h, hb, incb, outgb, indeg, outdeg, w1ut, w2ut, upb1, upb2,
                       lng, lnb, out);
  }
}

// Round 7
// 721.396 us; speedup vs baseline: 1.4098x; 1.0484x over previous
//
#include <hip/hip_runtime.h>
#include <stdint.h>

#define HIDD 128
#define NNODES 100000
#define NEDGES 800000
#define NSEG 196          // ceil(100000/512) segments for the scan

typedef short s16x8 __attribute__((ext_vector_type(8)));
typedef float f32x4 __attribute__((ext_vector_type(4)));

__device__ __forceinline__ short f2bf(float f) {
  union { float f; unsigned u; } v; v.f = f;
  return (short)((v.u + 0x7fffu + ((v.u >> 16) & 1u)) >> 16);
}
__device__ __forceinline__ short4 cvt4(float4 v) {
  short4 s; s.x = f2bf(v.x); s.y = f2bf(v.y); s.z = f2bf(v.z); s.w = f2bf(v.w);
  return s;
}
__device__ __forceinline__ float bflo(unsigned w) {
  union { unsigned u; float f; } v; v.u = w << 16; return v.f;
}
__device__ __forceinline__ float bfhi(unsigned w) {
  union { unsigned u; float f; } v; v.u = w & 0xffff0000u; return v.f;
}
__device__ __forceinline__ unsigned pack2(float a, float b) {
  return ((unsigned)(unsigned short)f2bf(b) << 16) | (unsigned)(unsigned short)f2bf(a);
}
__device__ __forceinline__ f32x4 mfma16(s16x8 a, s16x8 b, f32x4 c) {
  return __builtin_amdgcn_mfma_f32_16x16x32_bf16(a, b, c, 0, 0, 0);
}
__device__ __forceinline__ void atomic_pk_bf16(unsigned short* addr, unsigned pk) {
  asm volatile("global_atomic_pk_add_bf16 %0, %1, off" :: "v"(addr), "v"(pk) : "memory");
}

// ---------- prep: h -> bf16 ----------
__global__ void k_prep_h(const float4* __restrict__ h4, short4* __restrict__ hb4, int n4) {
  int stride = gridDim.x * blockDim.x;
  for (int i = blockIdx.x * blockDim.x + threadIdx.x; i < n4; i += stride)
    hb4[i] = cvt4(h4[i]);
}

// ---------- prep: weights -> bf16 [out][in]; w2e col-permuted ----------
__global__ void k_prep_w(const float* __restrict__ w1e, const float* __restrict__ w2e,
                         const float* __restrict__ w1u, const float* __restrict__ w2u,
                         short* __restrict__ w1et, short* __restrict__ w2et,
                         short* __restrict__ w1ut, short* __restrict__ w2ut) {
  int i = blockIdx.x * 256 + threadIdx.x;
  if (i < 49152) {               // dest [128][384]: n=i/384, k=i%384
    int n = i / 384, k = i - n * 384;
    w1et[i] = f2bf(w1e[k * 128 + n]);
    w1ut[i] = f2bf(w1u[k * 128 + n]);
  } else {
    int j = i - 49152;
    if (j < 16384) {             // dest [128][128]: n=j>>7, k=j&127
      int n = j >> 7, k = j & 127;
      int oc = (n & ~31) + 2 * (n & 15) + ((n >> 4) & 1);
      w2et[j] = f2bf(w2e[k * 128 + oc]);   // permuted
      w2ut[j] = f2bf(w2u[k * 128 + n]);    // natural
    }
  }
}

// ================= counting-sort chain =================
__global__ void k_hist(const int* __restrict__ eidx, int* __restrict__ cnt_s,
                       int* __restrict__ cnt_d) {
  int i = blockIdx.x * 256 + threadIdx.x;
  if (i < NEDGES) {
    atomicAdd(&cnt_s[eidx[i]], 1);
    atomicAdd(&cnt_d[eidx[NEDGES + i]], 1);
  }
}

__global__ void k_bsum(const int* __restrict__ cnt_d, const int* __restrict__ cnt_s,
                       int* __restrict__ bsum) {
  __shared__ int red[256];
  int gb = blockIdx.x, sel = gb >= NSEG, b = gb - sel * NSEG;
  const int* cnt = sel ? cnt_s : cnt_d;
  int t = threadIdx.x;
  int i0 = b * 512 + 2 * t;
  int a = (i0 < NNODES) ? cnt[i0] : 0;
  int c = (i0 + 1 < NNODES) ? cnt[i0 + 1] : 0;
  red[t] = a + c;
  __syncthreads();
  for (int d = 128; d > 0; d >>= 1) {
    if (t < d) red[t] += red[t + d];
    __syncthreads();
  }
  if (t == 0) bsum[gb] = red[0];
}

__global__ void k_soff(int* __restrict__ bsum, int* __restrict__ off_d,
                       int* __restrict__ off_s) {
  if (threadIdx.x == 0) {
    int tot = 0;
    for (int i = 0; i < NSEG; ++i) { int v = bsum[i]; bsum[i] = tot; tot += v; }
    off_d[NNODES] = tot;
  } else if (threadIdx.x == 1) {
    int tot = 0;
    for (int i = NSEG; i < 2 * NSEG; ++i) { int v = bsum[i]; bsum[i] = tot; tot += v; }
    off_s[NNODES] = tot;
  }
}

__global__ void k_sfin(const int* __restrict__ cnt_d, const int* __restrict__ cnt_s,
                       const int* __restrict__ bsum,
                       int* __restrict__ off_d, int* __restrict__ off_s,
                       int* __restrict__ cur_d, int* __restrict__ cur_s) {
  __shared__ int p[256];
  int gb = blockIdx.x, sel = gb >= NSEG, b = gb - sel * NSEG;
  const int* cnt = sel ? cnt_s : cnt_d;
  int* off = sel ? off_s : off_d;
  int* cur = sel ? cur_s : cur_d;
  int t = threadIdx.x;
  int i0 = b * 512 + 2 * t;
  int a = (i0 < NNODES) ? cnt[i0] : 0;
  int c = (i0 + 1 < NNODES) ? cnt[i0 + 1] : 0;
  p[t] = a + c;
  __syncthreads();
  for (int d = 1; d < 256; d <<= 1) {
    int v = (t >= d) ? p[t - d] : 0;
    __syncthreads();
    p[t] += v;
    __syncthreads();
  }
  int excl = (t ? p[t - 1] : 0) + bsum[gb];
  if (i0 < NNODES)     { off[i0] = excl;     cur[i0] = excl; }
  if (i0 + 1 < NNODES) { off[i0 + 1] = excl + a; cur[i0 + 1] = excl + a; }
}

// emit per-edge CSR slot (instead of edge lists)
__global__ void k_scat2(const int* __restrict__ eidx, int* __restrict__ cur_s,
                        int* __restrict__ cur_d, int* __restrict__ slot_s,
                        int* __restrict__ slot_d) {
  int i = blockIdx.x * 256 + threadIdx.x;
  if (i < NEDGES) {
    slot_s[i] = atomicAdd(&cur_s[eidx[i]], 1);
    slot_d[i] = atomicAdd(&cur_d[eidx[NEDGES + i]], 1);
  }
}

// ================= edge MLP -> messages stored in CSR order (both dirs) =================
__global__ __launch_bounds__(256, 2)
void k_edge2(const short* __restrict__ hb, const int* __restrict__ eidx,
             const float* __restrict__ ex,
             const short* __restrict__ w1t, const short* __restrict__ w2t,
             const float* __restrict__ b1g, const float* __restrict__ b2g,
             const int* __restrict__ slot_s, const int* __restrict__ slot_d,
             unsigned* __restrict__ msg_s, unsigned* __restrict__ msg_d) {
  __shared__ __align__(16) short Xs[64][392];   // 50176 B
  __shared__ __align__(16) short Hs[64][136];   // 17408 B
  __shared__ int Ss[64], Sd[64];                //   512 B

  const int tid = threadIdx.x;
  const int wave = tid >> 6, lane = tid & 63;
  const int lg = lane >> 4, lr = lane & 15;
  const int koff = lg * 8;
  const int c0 = wave * 32 + lr, c1 = c0 + 16;
  const int pc0 = wave * 32 + 2 * lr;   // natural col of frag0 (permuted W2)

  s16x8 wb1a[12], wb1b[12], wb2a[4], wb2b[4];
#pragma unroll
  for (int kk = 0; kk < 12; ++kk) {
    wb1a[kk] = *(const s16x8*)(w1t + c0 * 384 + kk * 32 + koff);
    wb1b[kk] = *(const s16x8*)(w1t + c1 * 384 + kk * 32 + koff);
  }
#pragma unroll
  for (int kk = 0; kk < 4; ++kk) {
    wb2a[kk] = *(const s16x8*)(w2t + c0 * 128 + kk * 32 + koff);
    wb2b[kk] = *(const s16x8*)(w2t + c1 * 128 + kk * 32 + koff);
  }
  const float bias1_0 = b1g[c0], bias1_1 = b1g[c1];
  const float bias2_0 = b2g[pc0], bias2_1 = b2g[pc0 + 1];

  for (int t = blockIdx.x; t < NEDGES / 64; t += gridDim.x) {
    const int base = t * 64;

    // Phase A: stage everything through LDS once per block (R4/R5 lesson)
    for (int u = tid; u < 64 * 32; u += 256) {
      int r = u >> 5, c = u & 31;
      int node = (c < 16) ? eidx[base + r] : eidx[NEDGES + base + r];
      *(int4*)&Xs[r][c * 8] = *(const int4*)(hb + (long)node * 128 + (c & 15) * 8);
    }
    for (int u = tid; u < 64 * 32; u += 256) {
      int r = u >> 5, q = u & 31;
      float4 v = *(const float4*)(ex + (long)(base + r) * 128 + q * 4);
      *(short4*)&Xs[r][256 + q * 4] = cvt4(v);
    }
    if (tid < 64) Ss[tid] = slot_s[base + tid];
    else if (tid < 128) Sd[tid - 64] = slot_d[base + tid - 64];
    __syncthreads();

    // Phase B: layer 1 + relu -> Hs
    f32x4 acc[4][2] = {};
#pragma unroll
    for (int kk = 0; kk < 12; ++kk) {
      int k0 = kk * 32 + koff;
#pragma unroll
      for (int m = 0; m < 4; ++m) {
        s16x8 a = *(const s16x8*)&Xs[m * 16 + lr][k0];
        acc[m][0] = mfma16(a, wb1a[kk], acc[m][0]);
        acc[m][1] = mfma16(a, wb1b[kk], acc[m][1]);
      }
    }
#pragma unroll
    for (int m = 0; m < 4; ++m)
#pragma unroll
      for (int r2 = 0; r2 < 4; ++r2) {
        int row = m * 16 + lg * 4 + r2;
        Hs[row][c0] = f2bf(fmaxf(acc[m][0][r2] + bias1_0, 0.f));
        Hs[row][c1] = f2bf(fmaxf(acc[m][1][r2] + bias1_1, 0.f));
      }
    __syncthreads();

    // Phase C: layer 2 + dual CSR-ordered store (no atomics)
    f32x4 acc2[4][2] = {};
#pragma unroll
    for (int kk = 0; kk < 4; ++kk) {
#pragma unroll
      for (int m = 0; m < 4; ++m) {
        s16x8 a = *(const s16x8*)&Hs[m * 16 + lr][kk * 32 + koff];
        acc2[m][0] = mfma16(a, wb2a[kk], acc2[m][0]);
        acc2[m][1] = mfma16(a, wb2b[kk], acc2[m][1]);
      }
    }
#pragma unroll
    for (int m = 0; m < 4; ++m)
#pragma unroll
      for (int r2 = 0; r2 < 4; ++r2) {
        int row = m * 16 + lg * 4 + r2;
        unsigned pk = pack2(acc2[m][0][r2] + bias2_0, acc2[m][1][r2] + bias2_1);
        int lo = wave * 16 + lr;
        msg_s[(long)Ss[row] * 64 + lo] = pk;
        msg_d[(long)Sd[row] * 64 + lo] = pk;
      }
    __syncthreads();   // Ss/Sd reads done before next tile's Phase A overwrites
  }
}

// ================= node: streaming CSR aggregate + MLP + LN =================
__global__ __launch_bounds__(256, 2)
void k_node2(const float* __restrict__ h, const short* __restrict__ hb,
             const unsigned* __restrict__ msg_d, const int* __restrict__ off_d,
             const unsigned* __restrict__ msg_s, const int* __restrict__ off_s,
             const short* __restrict__ w1t, const short* __restrict__ w2t,
             const float* __restrict__ b1g, const float* __restrict__ b2g,
             const float* __restrict__ lng, const float* __restrict__ lnb,
             float* __restrict__ out) {
  __shared__ __align__(16) char smem[67584];
  short (*Xs)[392] = (short (*)[392])smem;            // 50176 B
  float (*Xf)[132] = (float (*)[132])smem;            // overlay
  short (*Hs)[136] = (short (*)[136])(smem + 50176);  // 17408 B

  const int tid = threadIdx.x;
  const int wave = tid >> 6, lane = tid & 63;
  const int lg = lane >> 4, lr = lane & 15;
  const int koff = lg * 8;
  const int c0 = wave * 32 + lr, c1 = c0 + 16;

  s16x8 wb1a[12], wb1b[12], wb2a[4], wb2b[4];
#pragma unroll
  for (int kk = 0; kk < 12; ++kk) {
    wb1a[kk] = *(const s16x8*)(w1t + c0 * 384 + kk * 32 + koff);
    wb1b[kk] = *(const s16x8*)(w1t + c1 * 384 + kk * 32 + koff);
  }
#pragma unroll
  for (int kk = 0; kk < 4; ++kk) {
    wb2a[kk] = *(const s16x8*)(w2t + c0 * 128 + kk * 32 + koff);
    wb2b[kk] = *(const s16x8*)(w2t + c1 * 128 + kk * 32 + koff);
  }
  const float bias1_0 = b1g[c0], bias1_1 = b1g[c1];
  const float bias2_0 = b2g[c0], bias2_1 = b2g[c1];

  const int ntiles = (NNODES + 63) / 64;
  for (int t = blockIdx.x; t < ntiles; t += gridDim.x) {
    const int base = t * 64;

    // h copy
    for (int u = tid; u < 64 * 16; u += 256) {
      int r = u >> 4, c = u & 15;
      long node = min(base + r, NNODES - 1);
      *(int4*)&Xs[r][c * 8] = *(const int4*)(hb + node * 128 + c * 8);
    }
    // streaming aggregation: rows off[n]..off[n+1] are CONTIGUOUS per node
    {
      int r = tid >> 2, q = tid & 3;
      long node = base + r;
      bool valid = node < NNODES;
#pragma unroll
      for (int dir = 0; dir < 2; ++dir) {
        const int* off = dir ? off_s : off_d;
        const unsigned* msg = dir ? msg_s : msg_d;
        float av[32];
#pragma unroll
        for (int j = 0; j < 32; ++j) av[j] = 0.f;
        int e0 = 0, e1 = 0;
        if (valid) { e0 = off[node]; e1 = off[node + 1]; }
        for (int e = e0; e < e1; ++e) {
          const uint4* mp = (const uint4*)(msg + (long)e * 64 + q * 16);
          uint4 u0 = mp[0], u1 = mp[1], u2 = mp[2], u3 = mp[3];
          av[0]  += bflo(u0.x); av[1]  += bfhi(u0.x);
          av[2]  += bflo(u0.y); av[3]  += bfhi(u0.y);
          av[4]  += bflo(u0.z); av[5]  += bfhi(u0.z);
          av[6]  += bflo(u0.w); av[7]  += bfhi(u0.w);
          av[8]  += bflo(u1.x); av[9]  += bfhi(u1.x);
          av[10] += bflo(u1.y); av[11] += bfhi(u1.y);
          av[12] += bflo(u1.z); av[13] += bfhi(u1.z);
          av[14] += bflo(u1.w); av[15] += bfhi(u1.w);
          av[16] += bflo(u2.x); av[17] += bfhi(u2.x);
          av[18] += bflo(u2.y); av[19] += bfhi(u2.y);
          av[20] += bflo(u2.z); av[21] += bfhi(u2.z);
          av[22] += bflo(u2.w); av[23] += bfhi(u2.w);
          av[24] += bflo(u3.x); av[25] += bfhi(u3.x);
          av[26] += bflo(u3.y); av[27] += bfhi(u3.y);
          av[28] += bflo(u3.z); av[29] += bfhi(u3.z);
          av[30] += bflo(u3.w); av[31] += bfhi(u3.w);
        }
        float sc = 1.f / fmaxf((float)(e1 - e0), 1.f);
        unsigned pk[16];
#pragma unroll
        for (int j = 0; j < 16; ++j) pk[j] = pack2(av[2 * j] * sc, av[2 * j + 1] * sc);
        uint4* dst = (uint4*)&Xs[r][(dir ? 256 : 128) + q * 32];
        dst[0] = make_uint4(pk[0], pk[1], pk[2], pk[3]);
        dst[1] = make_uint4(pk[4], pk[5], pk[6], pk[7]);
        dst[2] = make_uint4(pk[8], pk[9], pk[10], pk[11]);
        dst[3] = make_uint4(pk[12], pk[13], pk[14], pk[15]);
      }
    }
    __syncthreads();

    // MLP layer 1
    f32x4 acc[4][2] = {};
#pragma unroll
    for (int kk = 0; kk < 12; ++kk) {
      int k0 = kk * 32 + koff;
#pragma unroll
      for (int m = 0; m < 4; ++m) {
        s16x8 a = *(const s16x8*)&Xs[m * 16 + lr][k0];
        acc[m][0] = mfma16(a, wb1a[kk], acc[m][0]);
        acc[m][1] = mfma16(a, wb1b[kk], acc[m][1]);
      }
    }
#pragma unroll
    for (int m = 0; m < 4; ++m)
#pragma unroll
      for (int r2 = 0; r2 < 4; ++r2) {
        int row = m * 16 + lg * 4 + r2;
        Hs[row][c0] = f2bf(fmaxf(acc[m][0][r2] + bias1_0, 0.f));
        Hs[row][c1] = f2bf(fmaxf(acc[m][1][r2] + bias1_1, 0.f));
      }
    __syncthreads();

    // MLP layer 2 + residual -> Xf
    f32x4 acc2[4][2] = {};
#pragma unroll
    for (int kk = 0; kk < 4; ++kk) {
      int k0 = kk * 32 + koff;
#pragma unroll
      for (int m = 0; m < 4; ++m) {
        s16x8 a = *(const s16x8*)&Hs[m * 16 + lr][k0];
        acc2[m][0] = mfma16(a, wb2a[kk], acc2[m][0]);
        acc2[m][1] = mfma16(a, wb2b[kk], acc2[m][1]);
      }
    }
#pragma unroll
    for (int m = 0; m < 4; ++m)
#pragma unroll
      for (int r2 = 0; r2 < 4; ++r2) {
        int row = m * 16 + lg * 4 + r2;
        long node = base + row;
        float h0 = 0.f, h1 = 0.f;
        if (node < NNODES) { h0 = h[node * 128 + c0]; h1 = h[node * 128 + c1]; }
        Xf[row][c0] = acc2[m][0][r2] + bias2_0 + h0;
        Xf[row][c1] = acc2[m][1][r2] + bias2_1 + h1;
      }
    __syncthreads();

    // LayerNorm + store
    {
      int r = tid >> 2, q = tid & 3;
      float sum = 0.f, ss = 0.f;
      float4 vals[8];
#pragma unroll
      for (int j = 0; j < 8; ++j) {
        float4 v = *(const float4*)&Xf[r][q * 32 + j * 4];
        vals[j] = v;
        sum += v.x + v.y + v.z + v.w;
        ss += v.x * v.x + v.y * v.y + v.z * v.z + v.w * v.w;
      }
      sum += __shfl_xor(sum, 1); sum += __shfl_xor(sum, 2);
      ss  += __shfl_xor(ss, 1);  ss  += __shfl_xor(ss, 2);
      float mean = sum * (1.f / 128.f);
      float var = ss * (1.f / 128.f) - mean * mean;
      float rstd = rsqrtf(var + 1e-5f);
      long node = base + r;
      if (node < NNODES) {
#pragma unroll
        for (int j = 0; j < 8; ++j) {
          int cc = q * 32 + j * 4;
          float4 v = vals[j];
          float4 o;
          o.x = (v.x - mean) * rstd * lng[cc + 0] + lnb[cc + 0];
          o.y = (v.y - mean) * rstd * lng[cc + 1] + lnb[cc + 1];
          o.z = (v.z - mean) * rstd * lng[cc + 2] + lnb[cc + 2];
          o.w = (v.w - mean) * rstd * lng[cc + 3] + lnb[cc + 3];
          *(float4*)(out + node * 128 + cc) = o;
        }
      }
    }
    __syncthreads();
  }
}

// ================= fallback path (R3, proven): pk-bf16 atomics =================
__global__ __launch_bounds__(256, 2)
void k_edge_at(const short* __restrict__ hb, const int* __restrict__ eidx,
               const float* __restrict__ ex,
               const short* __restrict__ w1t, const short* __restrict__ w2t,
               const float* __restrict__ b1g, const float* __restrict__ b2g,
               unsigned short* __restrict__ incb, unsigned short* __restrict__ outgb,
               float* __restrict__ indeg, float* __restrict__ outdeg) {
  __shared__ __align__(16) short Xs[64][392];
  __shared__ __align__(16) short Hs[64][136];
  const int tid = threadIdx.x;
  const int wave = tid >> 6, lane = tid & 63;
  const int lg = lane >> 4, lr = lane & 15;
  const int koff = lg * 8;
  const int c0 = wave * 32 + lr, c1 = c0 + 16;
  const int pc0 = wave * 32 + 2 * lr;
  s16x8 wb1a[12], wb1b[12], wb2a[4], wb2b[4];
#pragma unroll
  for (int kk = 0; kk < 12; ++kk) {
    wb1a[kk] = *(const s16x8*)(w1t + c0 * 384 + kk * 32 + koff);
    wb1b[kk] = *(const s16x8*)(w1t + c1 * 384 + kk * 32 + koff);
  }
#pragma unroll
  for (int kk = 0; kk < 4; ++kk) {
    wb2a[kk] = *(const s16x8*)(w2t + c0 * 128 + kk * 32 + koff);
    wb2b[kk] = *(const s16x8*)(w2t + c1 * 128 + kk * 32 + koff);
  }
  const float bias1_0 = b1g[c0], bias1_1 = b1g[c1];
  const float bias2_0 = b2g[pc0], bias2_1 = b2g[pc0 + 1];
  for (int t = blockIdx.x; t < NEDGES / 64; t += gridDim.x) {
    const int base = t * 64;
    for (int u = tid; u < 64 * 32; u += 256) {
      int r = u >> 5, c = u & 31;
      int node = (c < 16) ? eidx[base + r] : eidx[NEDGES + base + r];
      *(int4*)&Xs[r][c * 8] = *(const int4*)(hb + (long)node * 128 + (c & 15) * 8);
    }
    for (int u = tid; u < 64 * 32; u += 256) {
      int r = u >> 5, q = u & 31;
      float4 v = *(const float4*)(ex + (long)(base + r) * 128 + q * 4);
      *(short4*)&Xs[r][256 + q * 4] = cvt4(v);
    }
    if (tid < 64) {
      atomicAdd(&outdeg[eidx[base + tid]], 1.0f);
      atomicAdd(&indeg[eidx[NEDGES + base + tid]], 1.0f);
    }
    __syncthreads();
    f32x4 acc[4][2] = {};
#pragma unroll
    for (int kk = 0; kk < 12; ++kk) {
      int k0 = kk * 32 + koff;
#pragma unroll
      for (int m = 0; m < 4; ++m) {
        s16x8 a = *(const s16x8*)&Xs[m * 16 + lr][k0];
        acc[m][0] = mfma16(a, wb1a[kk], acc[m][0]);
        acc[m][1] = mfma16(a, wb1b[kk], acc[m][1]);
      }
    }
#pragma unroll
    for (int m = 0; m < 4; ++m)
#pragma unroll
      for (int r2 = 0; r2 < 4; ++r2) {
        int row = m * 16 + lg * 4 + r2;
        Hs[row][c0] = f2bf(fmaxf(acc[m][0][r2] + bias1_0, 0.f));
        Hs[row][c1] = f2bf(fmaxf(acc[m][1][r2] + bias1_1, 0.f));
      }
    __syncthreads();
    f32x4 acc2[4][2] = {};
#pragma unroll
    for (int kk = 0; kk < 4; ++kk) {
#pragma unroll
      for (int m = 0; m < 4; ++m) {
        s16x8 a = *(const s16x8*)&Hs[m * 16 + lr][kk * 32 + koff];
        acc2[m][0] = mfma16(a, wb2a[kk], acc2[m][0]);
        acc2[m][1] = mfma16(a, wb2b[kk], acc2[m][1]);
      }
    }
#pragma unroll
    for (int m = 0; m < 4; ++m)
#pragma unroll
      for (int r2 = 0; r2 < 4; ++r2) {
        int row = m * 16 + lg * 4 + r2;
        int s = eidx[base + row], d = eidx[NEDGES + base + row];
        unsigned pk = pack2(acc2[m][0][r2] + bias2_0, acc2[m][1][r2] + bias2_1);
        atomic_pk_bf16(outgb + (long)s * 128 + pc0, pk);
        atomic_pk_bf16(incb + (long)d * 128 + pc0, pk);
      }
  }
}

__global__ __launch_bounds__(256, 2)
void k_node_at(const float* __restrict__ h, const short* __restrict__ hb,
               const unsigned short* __restrict__ incb,
               const unsigned short* __restrict__ outgb,
               const float* __restrict__ indeg, const float* __restrict__ outdeg,
               const short* __restrict__ w1t, const short* __restrict__ w2t,
               const float* __restrict__ b1g, const float* __restrict__ b2g,
               const float* __restrict__ lng, const float* __restrict__ lnb,
               float* __restrict__ out) {
  __shared__ __align__(16) char smem[67584];
  short (*Xs)[392] = (short (*)[392])smem;
  float (*Xf)[132] = (float (*)[132])smem;
  short (*Hs)[136] = (short (*)[136])(smem + 50176);
  const int tid = threadIdx.x;
  const int wave = tid >> 6, lane = tid & 63;
  const int lg = lane >> 4, lr = lane & 15;
  const int koff = lg * 8;
  const int c0 = wave * 32 + lr, c1 = c0 + 16;
  s16x8 wb1a[12], wb1b[12], wb2a[4], wb2b[4];
#pragma unroll
  for (int kk = 0; kk < 12; ++kk) {
    wb1a[kk] = *(const s16x8*)(w1t + c0 * 384 + kk * 32 + koff);
    wb1b[kk] = *(const s16x8*)(w1t + c1 * 384 + kk * 32 + koff);
  }
#pragma unroll
  for (int kk = 0; kk < 4; ++kk) {
    wb2a[kk] = *(const s16x8*)(w2t + c0 * 128 + kk * 32 + koff);
    wb2b[kk] = *(const s16x8*)(w2t + c1 * 128 + kk * 32 + koff);
  }
  const float bias1_0 = b1g[c0], bias1_1 = b1g[c1];
  const float bias2_0 = b2g[c0], bias2_1 = b2g[c1];
  const int ntiles = (NNODES + 63) / 64;
  for (int t = blockIdx.x; t < ntiles; t += gridDim.x) {
    const int base = t * 64;
    for (int u = tid; u < 64 * 16; u += 256) {
      int r = u >> 4, c = u & 15;
      long node = min(base + r, NNODES - 1);
      *(int4*)&Xs[r][c * 8] = *(const int4*)(hb + node * 128 + c * 8);
    }
    for (int u = tid; u < 64 * 16; u += 256) {
      int r = u >> 4, c = u & 15;
      long node = min(base + r, NNODES - 1);
      float s = 1.f / fmaxf(indeg[node], 1.f);
      uint4 w = *(const uint4*)(incb + node * 128 + c * 8);
      *(uint4*)&Xs[r][128 + c * 8] = make_uint4(
        pack2(bflo(w.x) * s, bfhi(w.x) * s), pack2(bflo(w.y) * s, bfhi(w.y) * s),
        pack2(bflo(w.z) * s, bfhi(w.z) * s), pack2(bflo(w.w) * s, bfhi(w.w) * s));
    }
    for (int u = tid; u < 64 * 16; u += 256) {
      int r = u >> 4, c = u & 15;
      long node = min(base + r, NNODES - 1);
      float s = 1.f / fmaxf(outdeg[node], 1.f);
      uint4 w = *(const uint4*)(outgb + node * 128 + c * 8);
      *(uint4*)&Xs[r][256 + c * 8] = make_uint4(
        pack2(bflo(w.x) * s, bfhi(w.x) * s), pack2(bflo(w.y) * s, bfhi(w.y) * s),
        pack2(bflo(w.z) * s, bfhi(w.z) * s), pack2(bflo(w.w) * s, bfhi(w.w) * s));
    }
    __syncthreads();
    f32x4 acc[4][2] = {};
#pragma unroll
    for (int kk = 0; kk < 12; ++kk) {
      int k0 = kk * 32 + koff;
#pragma unroll
      for (int m = 0; m < 4; ++m) {
        s16x8 a = *(const s16x8*)&Xs[m * 16 + lr][k0];
        acc[m][0] = mfma16(a, wb1a[kk], acc[m][0]);
        acc[m][1] = mfma16(a, wb1b[kk], acc[m][1]);
      }
    }
#pragma unroll
    for (int m = 0; m < 4; ++m)
#pragma unroll
      for (int r2 = 0; r2 < 4; ++r2) {
        int row = m * 16 + lg * 4 + r2;
        Hs[row][c0] = f2bf(fmaxf(acc[m][0][r2] + bias1_0, 0.f));
        Hs[row][c1] = f2bf(fmaxf(acc[m][1][r2] + bias1_1, 0.f));
      }
    __syncthreads();
    f32x4 acc2[4][2] = {};
#pragma unroll
    for (int kk = 0; kk < 4; ++kk) {
      int k0 = kk * 32 + koff;
#pragma unroll
      for (int m = 0; m < 4; ++m) {
        s16x8 a = *(const s16x8*)&Hs[m * 16 + lr][k0];
        acc2[m][0] = mfma16(a, wb2a[kk], acc2[m][0]);
        acc2[m][1] = mfma16(a, wb2b[kk], acc2[m][1]);
      }
    }
#pragma unroll
    for (int m = 0; m < 4; ++m)
#pragma unroll
      for (int r2 = 0; r2 < 4; ++r2) {
        int row = m * 16 + lg * 4 + r2;
        long node = base + row;
        float h0 = 0.f, h1 = 0.f;
        if (node < NNODES) { h0 = h[node * 128 + c0]; h1 = h[node * 128 + c1]; }
        Xf[row][c0] = acc2[m][0][r2] + bias2_0 + h0;
        Xf[row][c1] = acc2[m][1][r2] + bias2_1 + h1;
      }
    __syncthreads();
    {
      int r = tid >> 2, q = tid & 3;
      float sum = 0.f, ss = 0.f;
      float4 vals[8];
#pragma unroll
      for (int j = 0; j < 8; ++j) {
        float4 v = *(const float4*)&Xf[r][q * 32 + j * 4];
        vals[j] = v;
        sum += v.x + v.y + v.z + v.w;
        ss += v.x * v.x + v.y * v.y + v.z * v.z + v.w * v.w;
      }
      sum += __shfl_xor(sum, 1); sum += __shfl_xor(sum, 2);
      ss  += __shfl_xor(ss, 1);  ss  += __shfl_xor(ss, 2);
      float mean = sum * (1.f / 128.f);
      float var = ss * (1.f / 128.f) - mean * mean;
      float rstd = rsqrtf(var + 1e-5f);
      long node = base + r;
      if (node < NNODES) {
#pragma unroll
        for (int j = 0; j < 8; ++j) {
          int cc = q * 32 + j * 4;
          float4 v = vals[j];
          float4 o;
          o.x = (v.x - mean) * rstd * lng[cc + 0] + lnb[cc + 0];
          o.y = (v.y - mean) * rstd * lng[cc + 1] + lnb[cc + 1];
          o.z = (v.z - mean) * rstd * lng[cc + 2] + lnb[cc + 2];
          o.w = (v.w - mean) * rstd * lng[cc + 3] + lnb[cc + 3];
          *(float4*)(out + node * 128 + cc) = o;
        }
      }
    }
    __syncthreads();
  }
}

extern "C" void kernel_launch(void* const* d_in, const int* in_sizes, int n_in,
                              void* d_out, int out_size, void* d_ws, size_t ws_size,
                              hipStream_t stream) {
  const float* h    = (const float*)d_in[0];
  const int*   ei   = (const int*)d_in[1];
  const float* ex   = (const float*)d_in[2];
  const float* epw1 = (const float*)d_in[3];
  const float* epb1 = (const float*)d_in[4];
  const float* epw2 = (const float*)d_in[5];
  const float* epb2 = (const float*)d_in[6];
  const float* upw1 = (const float*)d_in[7];
  const float* upb1 = (const float*)d_in[8];
  const float* upw2 = (const float*)d_in[9];
  const float* upb2 = (const float*)d_in[10];
  const float* lng  = (const float*)d_in[11];
  const float* lnb  = (const float*)d_in[12];
  float* out = (float*)d_out;
  char* ws = (char*)d_ws;

  const size_t NEED = 444300000ULL;
  if (ws_size >= NEED) {
    // ---------- sorted dual-store path (no value atomics, streaming reads) ----------
    unsigned* msg_s = (unsigned*)(ws);                      // 204,800,000
    unsigned* msg_d = (unsigned*)(ws + 204800000);          // 204,800,000
    short* hb    = (short*)(ws + 409600000);                //  25,600,000
    short* w1et  = (short*)(ws + 435200000);                //      98,304
    short* w2et  = (short*)(ws + 435298304);                //      32,768
    short* w1ut  = (short*)(ws + 435331072);                //      98,304
    short* w2ut  = (short*)(ws + 435429376);                //      32,768
    int* cnt_d   = (int*)(ws + 435462144);                  //     400,000
    int* cnt_s   = (int*)(ws + 435862144);                  //     400,000
    int* off_d   = (int*)(ws + 436262144);                  //     400,004
    int* off_s   = (int*)(ws + 436662148);                  //     400,004
    int* cur_d   = (int*)(ws + 437062152);                  //     400,000
    int* cur_s   = (int*)(ws + 437462152);                  //     400,000
    int* slot_s  = (int*)(ws + 437862152);                  //   3,200,000
    int* slot_d  = (int*)(ws + 441062152);                  //   3,200,000
    int* bsum    = (int*)(ws + 444262152);                  //       1,600

    hipMemsetAsync(cnt_d, 0, 800000, stream);               // cnt_d + cnt_s
    hipLaunchKernelGGL(k_prep_h, dim3(2048), dim3(256), 0, stream,
                       (const float4*)h, (short4*)hb, NNODES * 128 / 4);
    hipLaunchKernelGGL(k_prep_w, dim3(256), dim3(256), 0, stream,
                       epw1, epw2, upw1, upw2, w1et, w2et, w1ut, w2ut);
    hipLaunchKernelGGL(k_hist, dim3((NEDGES + 255) / 256), dim3(256), 0, stream,
                       ei, cnt_s, cnt_d);
    hipLaunchKernelGGL(k_bsum, dim3(2 * NSEG), dim3(256), 0, stream,
                       cnt_d, cnt_s, bsum);
    hipLaunchKernelGGL(k_soff, dim3(1), dim3(64), 0, stream, bsum, off_d, off_s);
    hipLaunchKernelGGL(k_sfin, dim3(2 * NSEG), dim3(256), 0, stream,
                       cnt_d, cnt_s, bsum, off_d, off_s, cur_d, cur_s);
    hipLaunchKernelGGL(k_scat2, dim3((NEDGES + 255) / 256), dim3(256), 0, stream,
                       ei, cur_s, cur_d, slot_s, slot_d);
    hipLaunchKernelGGL(k_edge2, dim3(1024), dim3(256), 0, stream,
                       hb, ei, ex, w1et, w2et, epb1, epb2, slot_s, slot_d,
                       msg_s, msg_d);
    hipLaunchKernelGGL(k_node2, dim3(512), dim3(256), 0, stream,
                       h, hb, msg_d, off_d, msg_s, off_s,
                       w1ut, w2ut, upb1, upb2, lng, lnb, out);
  } else {
    // ---------- fallback: proven R3 atomic path ----------
    unsigned short* incb  = (unsigned short*)(ws);             // 25,600,000
    unsigned short* outgb = (unsigned short*)(ws + 25600000);  // 25,600,000
    float* indeg  = (float*)(ws + 51200000);
    float* outdeg = (float*)(ws + 51600000);
    short* hb     = (short*)(ws + 52000000);
    short* w1et   = (short*)(ws + 77600000);
    short* w2et   = (short*)(ws + 77698304);
    short* w1ut   = (short*)(ws + 77731072);
    short* w2ut   = (short*)(ws + 77829376);

    hipMemsetAsync(ws, 0, 52000000, stream);
    hipLaunchKernelGGL(k_prep_h, dim3(2048), dim3(256), 0, stream,
                       (const float4*)h, (short4*)hb, NNODES * 128 / 4);
    hipLaunchKernelGGL(k_prep_w, dim3(256), dim3(256), 0, stream,
                       epw1, epw2, upw1, upw2, w1et, w2et, w1ut, w2ut);
    hipLaunchKernelGGL(k_edge_at, dim3(1024), dim3(256), 0, stream,
                       hb, ei, ex, w1et, w2et, epb1, epb2, incb, outgb, indeg, outdeg);
    hipLaunchKernelGGL(k_node_at, dim3(512), dim3(256), 0, stream,
                       h, hb, incb, outgb, indeg, outdeg, w1ut, w2ut, upb1, upb2,
                       lng, lnb, out);
  }
}